// Round 7
// baseline (4398.589 us; speedup 1.0000x reference)
//
#include <hip/hip_runtime.h>

#define Bn 64
#define Tn 2048
#define In 128
#define Hn 256
#define RS 512  // row stride in f16 elements for pre/out rows (1024 B)

typedef _Float16 h2 __attribute__((ext_vector_type(2)));
typedef _Float16 f16x8 __attribute__((ext_vector_type(8)));
typedef float f32x4 __attribute__((ext_vector_type(4)));

__device__ __forceinline__ float fast_sigmoid(float x) {
    return 1.0f / (1.0f + __expf(-x));
}
__device__ __forceinline__ float fast_tanh(float x) {
    return 2.0f / (1.0f + __expf(-2.0f * x)) - 1.0f;
}
__device__ __forceinline__ h2 bc2(float f) {
    return __builtin_bit_cast(h2, f);
}

#if __has_builtin(__builtin_amdgcn_fdot2)
__device__ __forceinline__ float dot2(h2 a, h2 b, float c) {
    return __builtin_amdgcn_fdot2(a, b, c, false);
}
#else
__device__ __forceinline__ float dot2(h2 a, h2 b, float c) {
    return c + (float)a.x * (float)b.x + (float)a.y * (float)b.y;
}
#endif

// ---------------------------------------------------------------------------
// K1: pre0[m][512] (f16, in d_out) = X[m][0:128] @ [Wih0 | Wax0] + [bh0 | ba0]
// ---------------------------------------------------------------------------
__global__ void gemm_x_kernel(const float* __restrict__ X,
                              const float* __restrict__ Wih0, const float* __restrict__ bh0,
                              const float* __restrict__ Wax0, const float* __restrict__ ba0,
                              _Float16* __restrict__ pre)
{
    __shared__ __align__(16) float Xs[64 * In];  // 32 KB
    const int m0 = blockIdx.x * 64;
    const int s  = blockIdx.y;
    const float* __restrict__ W    = s ? Wax0 : Wih0;
    const float* __restrict__ bias = s ? ba0  : bh0;

    {
        const float4* __restrict__ src = reinterpret_cast<const float4*>(X + (size_t)m0 * In);
        float4* __restrict__ dst = reinterpret_cast<float4*>(Xs);
        #pragma unroll
        for (int i = 0; i < 8; ++i) dst[threadIdx.x + 256 * i] = src[threadIdx.x + 256 * i];
    }
    __syncthreads();

    const int c  = threadIdx.x & 63;
    const int rg = threadIdx.x >> 6;
    const int mr = rg * 16;

    float acc[16][4];
    #pragma unroll
    for (int u = 0; u < 4; ++u) {
        const float bv = bias[c + 64 * u];
        #pragma unroll
        for (int r = 0; r < 16; ++r) acc[r][u] = bv;
    }

    const float4* __restrict__ Xs4 = reinterpret_cast<const float4*>(Xs);
    #pragma unroll 4
    for (int kc = 0; kc < 32; ++kc) {
        float wv[4][4];
        #pragma unroll
        for (int kk = 0; kk < 4; ++kk)
            #pragma unroll
            for (int u = 0; u < 4; ++u)
                wv[kk][u] = W[(size_t)(4 * kc + kk) * Hn + c + 64 * u];
        #pragma unroll
        for (int r = 0; r < 16; ++r) {
            const float4 xv = Xs4[(mr + r) * 32 + kc];
            #pragma unroll
            for (int u = 0; u < 4; ++u)
                acc[r][u] += xv.x * wv[0][u] + xv.y * wv[1][u] + xv.z * wv[2][u] + xv.w * wv[3][u];
        }
    }

    #pragma unroll
    for (int r = 0; r < 16; ++r)
        #pragma unroll
        for (int u = 0; u < 4; ++u)
            pre[(size_t)(m0 + mr + r) * RS + s * Hn + c + 64 * u] = (_Float16)acc[r][u];
}

// ---------------------------------------------------------------------------
// K3: pre1 (in-place over pre rows) = h0seq(f16) @ [Wih1 | Wax1] + bias
// ---------------------------------------------------------------------------
__global__ void gemm_h_kernel(_Float16* __restrict__ pre,
                              const float* __restrict__ Wih1, const float* __restrict__ bh1,
                              const float* __restrict__ Wax1, const float* __restrict__ ba1)
{
    __shared__ __align__(16) _Float16 Hs[32 * Hn];  // 16 KB
    const int m0 = blockIdx.x * 32;

    {
        float4* __restrict__ dst = reinterpret_cast<float4*>(Hs);
        #pragma unroll
        for (int q = 0; q < 4; ++q) {
            const int id  = threadIdx.x + 256 * q;
            const int row = id >> 5;
            const int off = id & 31;
            const float4* __restrict__ src =
                reinterpret_cast<const float4*>(pre + (size_t)(m0 + row) * RS);
            dst[row * 32 + off] = src[off];
        }
    }
    __syncthreads();

    const int c  = threadIdx.x & 63;
    const int rg = threadIdx.x >> 6;
    const int mr = rg * 8;

    const float* Wp[8];
    float acc[8][8];
    #pragma unroll
    for (int u = 0; u < 8; ++u) {
        const int colu = c + 64 * u;
        const float bv = (colu < Hn) ? bh1[colu] : ba1[colu - Hn];
        Wp[u] = (colu < Hn) ? (Wih1 + colu) : (Wax1 + (colu - Hn));
        #pragma unroll
        for (int r = 0; r < 8; ++r) acc[r][u] = bv;
    }

    const float2* __restrict__ Hs2 = reinterpret_cast<const float2*>(Hs);
    #pragma unroll 2
    for (int kc = 0; kc < 64; ++kc) {
        float wv[4][8];
        #pragma unroll
        for (int kk = 0; kk < 4; ++kk)
            #pragma unroll
            for (int u = 0; u < 8; ++u)
                wv[kk][u] = Wp[u][(size_t)(4 * kc + kk) * Hn];
        #pragma unroll
        for (int r = 0; r < 8; ++r) {
            const float2 q = Hs2[(mr + r) * 64 + kc];
            const h2 p0 = bc2(q.x), p1 = bc2(q.y);
            const float f0 = (float)p0.x, f1 = (float)p0.y, f2 = (float)p1.x, f3 = (float)p1.y;
            #pragma unroll
            for (int u = 0; u < 8; ++u)
                acc[r][u] += f0 * wv[0][u] + f1 * wv[1][u] + f2 * wv[2][u] + f3 * wv[3][u];
        }
    }

    #pragma unroll
    for (int r = 0; r < 8; ++r)
        #pragma unroll
        for (int u = 0; u < 8; ++u)
            pre[(size_t)(m0 + mr + r) * RS + c + 64 * u] = (_Float16)acc[r][u];
}

// ---------------------------------------------------------------------------
// Scan v7: identical to v6 except __launch_bounds__(512, 1).
//
// R6 evidence: with (512,2) the allocator capped at 128 arch VGPRs (the
// ~190 live values need more) and round-tripped weights through AGPRs,
// adding ~128 v_accvgpr copies per wave per step -> VALU time doubled and
// the dot2 win was erased. min-waves=1 frees the 256-VGPR arch budget
// (R2 precedent: (256,1) -> 188 VGPRs allocated). Runtime occupancy is
// unchanged (64 blocks of 8 waves on 256 CUs = 2 waves/SIMD regardless).
// ---------------------------------------------------------------------------
__global__ __launch_bounds__(512, 1)
void scan_dot2_kernel(_Float16* __restrict__ pre,
                      const float* __restrict__ WU, const float* __restrict__ WA,
                      float* __restrict__ outf, float* __restrict__ hfin, int writeF32)
{
    __shared__ __align__(16) _Float16 hbuf[2][Hn];   // 1 KB
    __shared__ __align__(16) float    abuf[Hn];      // 1 KB (published alpha)

    const int b   = blockIdx.x;
    const int tid = threadIdx.x;
    const int col = tid & 255;       // output column
    const int mv  = tid >> 8;        // 0 = U (tanh), 1 = A (sigmoid); wave-uniform

    // ---- weights: column `col` of this thread's matrix, h2-packed ----
    const float* __restrict__ Wm = mv ? WA : WU;
    h2 bw[128];
    #pragma unroll
    for (int k2 = 0; k2 < 128; ++k2) {
        h2 u;
        u.x = (_Float16)Wm[(size_t)(2 * k2)     * Hn + col];
        u.y = (_Float16)Wm[(size_t)(2 * k2 + 1) * Hn + col];
        bw[k2] = u;
    }

    _Float16* __restrict__ rowbase = pre + (size_t)b * Tn * RS;
    const int poff = mv ? Hn : 0;    // pre-activation offset for this matvec
    float hprev = 0.0f;              // live in mv=0 threads

    // prologue: h0 = 0; prefetch pre rows 0..7 (own matvec's half)
    if (tid < Hn) hbuf[0][tid] = (_Float16)0.0f;
    float pc[8];
    #pragma unroll
    for (int k = 0; k < 8; ++k)
        pc[k] = (float)rowbase[(size_t)k * RS + poff + col];
    __syncthreads();

    for (int t0 = 0; t0 < Tn; t0 += 8) {
        // ---- batched prefetch of rows t0+8 .. t0+15 ----
        float pn[8];
        #pragma unroll
        for (int k = 0; k < 8; ++k) {
            int tn = t0 + 8 + k;
            if (tn > Tn - 1) tn = Tn - 1;
            pn[k] = (float)rowbase[(size_t)tn * RS + poff + col];
        }

        float hst[8];   // chunk store batch (mv=0 threads)

        #pragma unroll
        for (int ph = 0; ph < 8; ++ph) {
            const int t = t0 + ph;

            const f16x8* __restrict__ hb =
                reinterpret_cast<const f16x8*>(&hbuf[t & 1][0]);

            float acc[4] = {0.0f, 0.0f, 0.0f, 0.0f};

            // 32 broadcast b128 reads; 4 h2-pairs each; 4 indep dot chains
            #pragma unroll
            for (int r = 0; r < 32; ++r) {
                const f16x8 v = hb[r];                       // h[8r .. 8r+7]
                const h2 p0 = __builtin_shufflevector(v, v, 0, 1);
                const h2 p1 = __builtin_shufflevector(v, v, 2, 3);
                const h2 p2 = __builtin_shufflevector(v, v, 4, 5);
                const h2 p3 = __builtin_shufflevector(v, v, 6, 7);
                acc[0] = dot2(p0, bw[4 * r + 0], acc[0]);
                acc[1] = dot2(p1, bw[4 * r + 1], acc[1]);
                acc[2] = dot2(p2, bw[4 * r + 2], acc[2]);
                acc[3] = dot2(p3, bw[4 * r + 3], acc[3]);
            }
            const float y = (acc[0] + acc[1]) + (acc[2] + acc[3]) + pc[ph];

            // pre-barrier nonlinearity (off the critical path)
            float cand = 0.0f;
            if (mv) {
                abuf[col] = fast_sigmoid(y);   // publish alpha
            } else {
                cand = fast_tanh(y);
            }
            __syncthreads();   // alpha ready; all hbuf[t&1] reads done

            if (!mv) {
                const float alpha = abuf[col];
                const float hn = hprev + alpha * (cand - hprev);
                hprev = hn;
                hst[ph] = hn;
                hbuf[(t + 1) & 1][col] = (_Float16)hn;
            }
            __syncthreads();   // hbuf[(t+1)&1] ready; abuf reads done
        }

        // ---- chunk flush: batched global stores + rotate prefetch regs ----
        if (!mv) {
            if (writeF32) {
                #pragma unroll
                for (int k = 0; k < 8; ++k)
                    outf[((size_t)b * Tn + (t0 + k)) * Hn + col] = hst[k];
            } else {
                #pragma unroll
                for (int k = 0; k < 8; ++k)
                    rowbase[(size_t)(t0 + k) * RS + col] = (_Float16)hst[k];
            }
        }
        #pragma unroll
        for (int k = 0; k < 8; ++k) pc[k] = pn[k];
    }

    if (!mv) hfin[b * Hn + col] = hprev;
}

extern "C" void kernel_launch(void* const* d_in, const int* in_sizes, int n_in,
                              void* d_out, int out_size, void* d_ws, size_t ws_size,
                              hipStream_t stream) {
    const float* X    = (const float*)d_in[0];
    const float* Wih0 = (const float*)d_in[1];
    const float* Whh0 = (const float*)d_in[2];
    const float* bh0  = (const float*)d_in[3];
    const float* Wax0 = (const float*)d_in[4];
    const float* Wah0 = (const float*)d_in[5];
    const float* ba0  = (const float*)d_in[6];
    const float* Wih1 = (const float*)d_in[7];
    const float* Whh1 = (const float*)d_in[8];
    const float* bh1  = (const float*)d_in[9];
    const float* Wax1 = (const float*)d_in[10];
    const float* Wah1 = (const float*)d_in[11];
    const float* ba1  = (const float*)d_in[12];

    float* outf = (float*)d_out;
    float* hfin = outf + (size_t)Bn * Tn * Hn;
    _Float16* pre = (_Float16*)d_out;

    gemm_x_kernel<<<dim3((Bn * Tn) / 64, 2), 256, 0, stream>>>(X, Wih0, bh0, Wax0, ba0, pre);
    scan_dot2_kernel<<<dim3(Bn), 512, 0, stream>>>(pre, Whh0, Wah0, outf, hfin, 0);
    gemm_h_kernel<<<dim3((Bn * Tn) / 32), 256, 0, stream>>>(pre, Wih1, bh1, Wax1, ba1);
    scan_dot2_kernel<<<dim3(Bn), 512, 0, stream>>>(pre, Whh1, Wah1, outf, hfin + Bn * Hn, 1);
}

// Round 9
// 4305.180 us; speedup vs baseline: 1.0217x; 1.0217x over previous
//
#include <hip/hip_runtime.h>

#define Bn 64
#define Tn 2048
#define In 128
#define Hn 256
#define RS 512  // row stride in f16 elements for pre/out rows (1024 B)

typedef _Float16 h2 __attribute__((ext_vector_type(2)));
typedef _Float16 f16x8 __attribute__((ext_vector_type(8)));

__device__ __forceinline__ float fast_sigmoid(float x) {
    return 1.0f / (1.0f + __expf(-x));
}
__device__ __forceinline__ float fast_tanh(float x) {
    return 2.0f / (1.0f + __expf(-2.0f * x)) - 1.0f;
}
__device__ __forceinline__ h2 bc2(float f) {
    return __builtin_bit_cast(h2, f);
}

#if __has_builtin(__builtin_amdgcn_fdot2)
__device__ __forceinline__ float dot2(h2 a, h2 b, float c) {
    return __builtin_amdgcn_fdot2(a, b, c, false);
}
#else
__device__ __forceinline__ float dot2(h2 a, h2 b, float c) {
    return c + (float)a.x * (float)b.x + (float)a.y * (float)b.y;
}
#endif

// ---------------------------------------------------------------------------
// K1: pre0[m][512] (f16, in d_out) = X[m][0:128] @ [Wih0 | Wax0] + [bh0 | ba0]
// ---------------------------------------------------------------------------
__global__ void gemm_x_kernel(const float* __restrict__ X,
                              const float* __restrict__ Wih0, const float* __restrict__ bh0,
                              const float* __restrict__ Wax0, const float* __restrict__ ba0,
                              _Float16* __restrict__ pre)
{
    __shared__ __align__(16) float Xs[64 * In];  // 32 KB
    const int m0 = blockIdx.x * 64;
    const int s  = blockIdx.y;
    const float* __restrict__ W    = s ? Wax0 : Wih0;
    const float* __restrict__ bias = s ? ba0  : bh0;

    {
        const float4* __restrict__ src = reinterpret_cast<const float4*>(X + (size_t)m0 * In);
        float4* __restrict__ dst = reinterpret_cast<float4*>(Xs);
        #pragma unroll
        for (int i = 0; i < 8; ++i) dst[threadIdx.x + 256 * i] = src[threadIdx.x + 256 * i];
    }
    __syncthreads();

    const int c  = threadIdx.x & 63;
    const int rg = threadIdx.x >> 6;
    const int mr = rg * 16;

    float acc[16][4];
    #pragma unroll
    for (int u = 0; u < 4; ++u) {
        const float bv = bias[c + 64 * u];
        #pragma unroll
        for (int r = 0; r < 16; ++r) acc[r][u] = bv;
    }

    const float4* __restrict__ Xs4 = reinterpret_cast<const float4*>(Xs);
    #pragma unroll 4
    for (int kc = 0; kc < 32; ++kc) {
        float wv[4][4];
        #pragma unroll
        for (int kk = 0; kk < 4; ++kk)
            #pragma unroll
            for (int u = 0; u < 4; ++u)
                wv[kk][u] = W[(size_t)(4 * kc + kk) * Hn + c + 64 * u];
        #pragma unroll
        for (int r = 0; r < 16; ++r) {
            const float4 xv = Xs4[(mr + r) * 32 + kc];
            #pragma unroll
            for (int u = 0; u < 4; ++u)
                acc[r][u] += xv.x * wv[0][u] + xv.y * wv[1][u] + xv.z * wv[2][u] + xv.w * wv[3][u];
        }
    }

    #pragma unroll
    for (int r = 0; r < 16; ++r)
        #pragma unroll
        for (int u = 0; u < 4; ++u)
            pre[(size_t)(m0 + mr + r) * RS + s * Hn + c + 64 * u] = (_Float16)acc[r][u];
}

// ---------------------------------------------------------------------------
// K3: pre1 (in-place over pre rows) = h0seq(f16) @ [Wih1 | Wax1] + bias
// ---------------------------------------------------------------------------
__global__ void gemm_h_kernel(_Float16* __restrict__ pre,
                              const float* __restrict__ Wih1, const float* __restrict__ bh1,
                              const float* __restrict__ Wax1, const float* __restrict__ ba1)
{
    __shared__ __align__(16) _Float16 Hs[32 * Hn];  // 16 KB
    const int m0 = blockIdx.x * 32;

    {
        float4* __restrict__ dst = reinterpret_cast<float4*>(Hs);
        #pragma unroll
        for (int q = 0; q < 4; ++q) {
            const int id  = threadIdx.x + 256 * q;
            const int row = id >> 5;
            const int off = id & 31;
            const float4* __restrict__ src =
                reinterpret_cast<const float4*>(pre + (size_t)(m0 + row) * RS);
            dst[row * 32 + off] = src[off];
        }
    }
    __syncthreads();

    const int c  = threadIdx.x & 63;
    const int rg = threadIdx.x >> 6;
    const int mr = rg * 8;

    const float* Wp[8];
    float acc[8][8];
    #pragma unroll
    for (int u = 0; u < 8; ++u) {
        const int colu = c + 64 * u;
        const float bv = (colu < Hn) ? bh1[colu] : ba1[colu - Hn];
        Wp[u] = (colu < Hn) ? (Wih1 + colu) : (Wax1 + (colu - Hn));
        #pragma unroll
        for (int r = 0; r < 8; ++r) acc[r][u] = bv;
    }

    const float2* __restrict__ Hs2 = reinterpret_cast<const float2*>(Hs);
    #pragma unroll 2
    for (int kc = 0; kc < 64; ++kc) {
        float wv[4][8];
        #pragma unroll
        for (int kk = 0; kk < 4; ++kk)
            #pragma unroll
            for (int u = 0; u < 8; ++u)
                wv[kk][u] = Wp[u][(size_t)(4 * kc + kk) * Hn];
        #pragma unroll
        for (int r = 0; r < 8; ++r) {
            const float2 q = Hs2[(mr + r) * 64 + kc];
            const h2 p0 = bc2(q.x), p1 = bc2(q.y);
            const float f0 = (float)p0.x, f1 = (float)p0.y, f2 = (float)p1.x, f3 = (float)p1.y;
            #pragma unroll
            for (int u = 0; u < 8; ++u)
                acc[r][u] += f0 * wv[0][u] + f1 * wv[1][u] + f2 * wv[2][u] + f3 * wv[3][u];
        }
    }

    #pragma unroll
    for (int r = 0; r < 8; ++r)
        #pragma unroll
        for (int u = 0; u < 8; ++u)
            pre[(size_t)(m0 + mr + r) * RS + c + 64 * u] = (_Float16)acc[r][u];
}

// ---------------------------------------------------------------------------
// Scan v8: dot2 with 4-way K-split to fit the 128-VGPR envelope.
//
// R6/R7 evidence: blocks with >=8 waves are hard-capped at 128 arch VGPRs
// (2 waves/SIMD minimum); holding 128 weight h2 regs forced ~128 AGPR
// round-trip copies per step, doubling VALU time. Fix: 1024 threads
// (16 waves, 4/SIMD); thread (kq, col) holds BOTH matrices' weights for
// only its 64-row K-quarter = 64 h2 VGPRs; total live ~120 < 128.
//
// Step: all threads compute (partU, partA) for their K-quarter (64 fdot2,
// h via 8 broadcast b128 reads of their quarter); kq=1..3 publish float2
// partials to pbuf (kq=1 folds its prefetched pA in); barrier; kq=0
// combines + pU, activation in-lane (hprev in register), writes hbuf;
// barrier. Per-SIMD dot2 issue: 4 waves x 64 x 2cy = 512 cy (the VALU
// floor). Chunked prefetch: pU in kq=0 threads, pA in kq=1; chunk-end
// batched global stores from kq=0 (R2-proven).
// ---------------------------------------------------------------------------
__global__ __launch_bounds__(1024, 4)
void scan_dot2_kernel(_Float16* __restrict__ pre,
                      const float* __restrict__ WU, const float* __restrict__ WA,
                      float* __restrict__ outf, float* __restrict__ hfin, int writeF32)
{
    __shared__ __align__(16) _Float16 hbuf[2][Hn];   // 1 KB
    __shared__ __align__(16) float2   pbuf[3][Hn];   // 6 KB (partU, partA)

    const int b   = blockIdx.x;
    const int tid = threadIdx.x;
    const int col = tid & 255;       // output column
    const int kq  = tid >> 8;        // K-quarter 0..3 (wave-uniform)

    // ---- weights: K rows [64kq, 64kq+64) of column `col`, both matrices ----
    h2 bwU[32], bwA[32];
    #pragma unroll
    for (int i = 0; i < 32; ++i) {
        const int k0 = 64 * kq + 2 * i;
        h2 u, a;
        u.x = (_Float16)WU[(size_t)k0 * Hn + col];
        u.y = (_Float16)WU[(size_t)(k0 + 1) * Hn + col];
        a.x = (_Float16)WA[(size_t)k0 * Hn + col];
        a.y = (_Float16)WA[(size_t)(k0 + 1) * Hn + col];
        bwU[i] = u;
        bwA[i] = a;
    }

    _Float16* __restrict__ rowbase = pre + (size_t)b * Tn * RS;
    float hprev = 0.0f;              // live in kq=0 threads

    // prologue: h0 = 0; kq=0 prefetches pU rows 0..7, kq=1 prefetches pA
    if (tid < Hn) hbuf[0][tid] = (_Float16)0.0f;
    float pc[8];
    if (kq < 2) {
        const int off = kq ? Hn : 0;
        #pragma unroll
        for (int k = 0; k < 8; ++k)
            pc[k] = (float)rowbase[(size_t)k * RS + off + col];
    }
    __syncthreads();

    for (int t0 = 0; t0 < Tn; t0 += 8) {
        // ---- batched prefetch of rows t0+8 .. t0+15 (kq=0: pU, kq=1: pA) ----
        float pn[8];
        if (kq < 2) {
            const int off = kq ? Hn : 0;
            #pragma unroll
            for (int k = 0; k < 8; ++k) {
                int tn = t0 + 8 + k;
                if (tn > Tn - 1) tn = Tn - 1;
                pn[k] = (float)rowbase[(size_t)tn * RS + off + col];
            }
        }

        float hst[8];   // chunk store batch (kq=0 threads)

        #pragma unroll
        for (int ph = 0; ph < 8; ++ph) {
            const int t = t0 + ph;

            // ---- this K-quarter of h: 8 broadcast b128 reads ----
            const f16x8* __restrict__ hb =
                reinterpret_cast<const f16x8*>(&hbuf[t & 1][64 * kq]);

            float aU[2] = {0.0f, 0.0f};
            float aA[2] = {0.0f, 0.0f};
            #pragma unroll
            for (int r = 0; r < 8; ++r) {
                const f16x8 v = hb[r];                       // h[8r .. 8r+7] of quarter
                const h2 p0 = __builtin_shufflevector(v, v, 0, 1);
                const h2 p1 = __builtin_shufflevector(v, v, 2, 3);
                const h2 p2 = __builtin_shufflevector(v, v, 4, 5);
                const h2 p3 = __builtin_shufflevector(v, v, 6, 7);
                aU[0] = dot2(p0, bwU[4 * r + 0], aU[0]);
                aU[1] = dot2(p1, bwU[4 * r + 1], aU[1]);
                aU[0] = dot2(p2, bwU[4 * r + 2], aU[0]);
                aU[1] = dot2(p3, bwU[4 * r + 3], aU[1]);
                aA[0] = dot2(p0, bwA[4 * r + 0], aA[0]);
                aA[1] = dot2(p1, bwA[4 * r + 1], aA[1]);
                aA[0] = dot2(p2, bwA[4 * r + 2], aA[0]);
                aA[1] = dot2(p3, bwA[4 * r + 3], aA[1]);
            }
            float partU = aU[0] + aU[1];
            float partA = aA[0] + aA[1];
            if (kq == 1) partA += pc[ph];        // fold prefetched pA

            if (kq) pbuf[kq - 1][col] = make_float2(partU, partA);
            __syncthreads();   // partials ready; h reads of this step done

            if (kq == 0) {
                const float2 q0 = pbuf[0][col];
                const float2 q1 = pbuf[1][col];
                const float2 q2 = pbuf[2][col];
                const float yU = partU + q0.x + q1.x + q2.x + pc[ph];
                const float yA = partA + q0.y + q1.y + q2.y;
                const float cand  = fast_tanh(yU);
                const float alpha = fast_sigmoid(yA);
                const float hn = hprev + alpha * (cand - hprev);
                hprev = hn;
                hst[ph] = hn;
                hbuf[(t + 1) & 1][col] = (_Float16)hn;
            }
            __syncthreads();   // hbuf[(t+1)&1] ready; pbuf reads done
        }

        // ---- chunk flush: batched global stores + rotate prefetch regs ----
        if (kq == 0) {
            if (writeF32) {
                #pragma unroll
                for (int k = 0; k < 8; ++k)
                    outf[((size_t)b * Tn + (t0 + k)) * Hn + col] = hst[k];
            } else {
                #pragma unroll
                for (int k = 0; k < 8; ++k)
                    rowbase[(size_t)(t0 + k) * RS + col] = (_Float16)hst[k];
            }
        }
        if (kq < 2) {
            #pragma unroll
            for (int k = 0; k < 8; ++k) pc[k] = pn[k];
        }
    }

    if (kq == 0) hfin[b * Hn + col] = hprev;
}

extern "C" void kernel_launch(void* const* d_in, const int* in_sizes, int n_in,
                              void* d_out, int out_size, void* d_ws, size_t ws_size,
                              hipStream_t stream) {
    const float* X    = (const float*)d_in[0];
    const float* Wih0 = (const float*)d_in[1];
    const float* Whh0 = (const float*)d_in[2];
    const float* bh0  = (const float*)d_in[3];
    const float* Wax0 = (const float*)d_in[4];
    const float* Wah0 = (const float*)d_in[5];
    const float* ba0  = (const float*)d_in[6];
    const float* Wih1 = (const float*)d_in[7];
    const float* Whh1 = (const float*)d_in[8];
    const float* bh1  = (const float*)d_in[9];
    const float* Wax1 = (const float*)d_in[10];
    const float* Wah1 = (const float*)d_in[11];
    const float* ba1  = (const float*)d_in[12];

    float* outf = (float*)d_out;
    float* hfin = outf + (size_t)Bn * Tn * Hn;
    _Float16* pre = (_Float16*)d_out;

    gemm_x_kernel<<<dim3((Bn * Tn) / 64, 2), 256, 0, stream>>>(X, Wih0, bh0, Wax0, ba0, pre);
    scan_dot2_kernel<<<dim3(Bn), 1024, 0, stream>>>(pre, Whh0, Wah0, outf, hfin, 0);
    gemm_h_kernel<<<dim3((Bn * Tn) / 32), 256, 0, stream>>>(pre, Wih1, bh1, Wax1, ba1);
    scan_dot2_kernel<<<dim3(Bn), 1024, 0, stream>>>(pre, Whh1, Wah1, outf, hfin + Bn * Hn, 1);
}

// Round 10
// 3832.950 us; speedup vs baseline: 1.1476x; 1.1232x over previous
//
#include <hip/hip_runtime.h>

#define Bn 64
#define Tn 2048
#define In 128
#define Hn 256
#define RS 512  // row stride in f16 elements for pre/out rows (1024 B)

typedef _Float16 h2 __attribute__((ext_vector_type(2)));
typedef _Float16 f16x8 __attribute__((ext_vector_type(8)));
typedef float f32x4 __attribute__((ext_vector_type(4)));

__device__ __forceinline__ float fast_sigmoid(float x) {
    return 1.0f / (1.0f + __expf(-x));
}
__device__ __forceinline__ float fast_tanh(float x) {
    return 2.0f / (1.0f + __expf(-2.0f * x)) - 1.0f;
}
__device__ __forceinline__ h2 bc2(float f) {
    return __builtin_bit_cast(h2, f);
}

#if __has_builtin(__builtin_amdgcn_fdot2)
__device__ __forceinline__ float dot2(h2 a, h2 b, float c) {
    return __builtin_amdgcn_fdot2(a, b, c, false);
}
#else
__device__ __forceinline__ float dot2(h2 a, h2 b, float c) {
    return c + (float)a.x * (float)b.x + (float)a.y * (float)b.y;
}
#endif

// ---------------------------------------------------------------------------
// K1: pre0[m][512] (f16, in d_out) = X[m][0:128] @ [Wih0 | Wax0] + [bh0 | ba0]
// ---------------------------------------------------------------------------
__global__ void gemm_x_kernel(const float* __restrict__ X,
                              const float* __restrict__ Wih0, const float* __restrict__ bh0,
                              const float* __restrict__ Wax0, const float* __restrict__ ba0,
                              _Float16* __restrict__ pre)
{
    __shared__ __align__(16) float Xs[64 * In];  // 32 KB
    const int m0 = blockIdx.x * 64;
    const int s  = blockIdx.y;
    const float* __restrict__ W    = s ? Wax0 : Wih0;
    const float* __restrict__ bias = s ? ba0  : bh0;

    {
        const float4* __restrict__ src = reinterpret_cast<const float4*>(X + (size_t)m0 * In);
        float4* __restrict__ dst = reinterpret_cast<float4*>(Xs);
        #pragma unroll
        for (int i = 0; i < 8; ++i) dst[threadIdx.x + 256 * i] = src[threadIdx.x + 256 * i];
    }
    __syncthreads();

    const int c  = threadIdx.x & 63;
    const int rg = threadIdx.x >> 6;
    const int mr = rg * 16;

    float acc[16][4];
    #pragma unroll
    for (int u = 0; u < 4; ++u) {
        const float bv = bias[c + 64 * u];
        #pragma unroll
        for (int r = 0; r < 16; ++r) acc[r][u] = bv;
    }

    const float4* __restrict__ Xs4 = reinterpret_cast<const float4*>(Xs);
    #pragma unroll 4
    for (int kc = 0; kc < 32; ++kc) {
        float wv[4][4];
        #pragma unroll
        for (int kk = 0; kk < 4; ++kk)
            #pragma unroll
            for (int u = 0; u < 4; ++u)
                wv[kk][u] = W[(size_t)(4 * kc + kk) * Hn + c + 64 * u];
        #pragma unroll
        for (int r = 0; r < 16; ++r) {
            const float4 xv = Xs4[(mr + r) * 32 + kc];
            #pragma unroll
            for (int u = 0; u < 4; ++u)
                acc[r][u] += xv.x * wv[0][u] + xv.y * wv[1][u] + xv.z * wv[2][u] + xv.w * wv[3][u];
        }
    }

    #pragma unroll
    for (int r = 0; r < 16; ++r)
        #pragma unroll
        for (int u = 0; u < 4; ++u)
            pre[(size_t)(m0 + mr + r) * RS + s * Hn + c + 64 * u] = (_Float16)acc[r][u];
}

// ---------------------------------------------------------------------------
// Fused two-layer scan with cross-block chunk pipeline.
// Blocks 0..63  : layer-0 scan (R9 dot2 K-split body) + per-chunk RELEASE of
//                 prog[b] after storing the chunk's h0 rows (f16, in-place in
//                 the pre0 U-half).
// Blocks 64..127: layer-1 for b = blockIdx.x-64. Per chunk: ACQUIRE prog[b],
//                 load 8 h0 rows -> LDS, MFMA mini-GEMM (M=8 timesteps) to
//                 produce pre1 rows in LDS (replaces gemm_h entirely), then
//                 8 scan steps (R9 dot2 body, pre from LDS), then outf f32
//                 stores (over the consumed pre0 bytes - ordered by the flag).
// Sync: __hip_atomic_ release/acquire at agent scope (Guideline 16).
// ---------------------------------------------------------------------------
__global__ __launch_bounds__(1024, 4)
void fused_scan(_Float16* __restrict__ pre,
                const float* __restrict__ WU0, const float* __restrict__ WA0,
                const float* __restrict__ Wih1, const float* __restrict__ Wax1,
                const float* __restrict__ bh1,  const float* __restrict__ ba1,
                const float* __restrict__ WU1,  const float* __restrict__ WA1,
                float* __restrict__ outf, float* __restrict__ hfin,
                int* __restrict__ prog)
{
    __shared__ __align__(16) _Float16 hbuf[2][Hn];        // 1 KB
    __shared__ __align__(16) float2   pbuf[3][Hn];        // 6 KB
    __shared__ __align__(16) _Float16 h0t[8][Hn + 8];     // 4.2 KB (pad: bank spread)
    __shared__ __align__(16) _Float16 preL[8][2 * Hn + 8];// 8.3 KB (pad: bank spread)

    const int tid  = threadIdx.x;
    const int col  = tid & 255;
    const int kq   = tid >> 8;
    const int lane = tid & 63;
    const int w    = tid >> 6;
    const int g    = lane >> 4;
    const int cl   = lane & 15;

    if (blockIdx.x < Bn) {
        // ========================= layer 0 =========================
        const int b = blockIdx.x;
        h2 bwU[32], bwA[32];
        #pragma unroll
        for (int i = 0; i < 32; ++i) {
            const int k0 = 64 * kq + 2 * i;
            h2 u, a;
            u.x = (_Float16)WU0[(size_t)k0 * Hn + col];
            u.y = (_Float16)WU0[(size_t)(k0 + 1) * Hn + col];
            a.x = (_Float16)WA0[(size_t)k0 * Hn + col];
            a.y = (_Float16)WA0[(size_t)(k0 + 1) * Hn + col];
            bwU[i] = u;
            bwA[i] = a;
        }

        _Float16* __restrict__ rowbase = pre + (size_t)b * Tn * RS;
        float hprev = 0.0f;

        if (tid < Hn) hbuf[0][tid] = (_Float16)0.0f;
        float pc[8];
        if (kq < 2) {
            const int off = kq ? Hn : 0;
            #pragma unroll
            for (int k = 0; k < 8; ++k)
                pc[k] = (float)rowbase[(size_t)k * RS + off + col];
        }
        __syncthreads();

        for (int t0 = 0; t0 < Tn; t0 += 8) {
            float pn[8];
            if (kq < 2) {
                const int off = kq ? Hn : 0;
                #pragma unroll
                for (int k = 0; k < 8; ++k) {
                    int tn = t0 + 8 + k;
                    if (tn > Tn - 1) tn = Tn - 1;
                    pn[k] = (float)rowbase[(size_t)tn * RS + off + col];
                }
            }

            float hst[8];

            #pragma unroll
            for (int ph = 0; ph < 8; ++ph) {
                const int t = t0 + ph;
                const f16x8* __restrict__ hb =
                    reinterpret_cast<const f16x8*>(&hbuf[t & 1][64 * kq]);

                float aU[2] = {0.0f, 0.0f};
                float aA[2] = {0.0f, 0.0f};
                #pragma unroll
                for (int r = 0; r < 8; ++r) {
                    const f16x8 v = hb[r];
                    const h2 p0 = __builtin_shufflevector(v, v, 0, 1);
                    const h2 p1 = __builtin_shufflevector(v, v, 2, 3);
                    const h2 p2 = __builtin_shufflevector(v, v, 4, 5);
                    const h2 p3 = __builtin_shufflevector(v, v, 6, 7);
                    aU[0] = dot2(p0, bwU[4 * r + 0], aU[0]);
                    aU[1] = dot2(p1, bwU[4 * r + 1], aU[1]);
                    aU[0] = dot2(p2, bwU[4 * r + 2], aU[0]);
                    aU[1] = dot2(p3, bwU[4 * r + 3], aU[1]);
                    aA[0] = dot2(p0, bwA[4 * r + 0], aA[0]);
                    aA[1] = dot2(p1, bwA[4 * r + 1], aA[1]);
                    aA[0] = dot2(p2, bwA[4 * r + 2], aA[0]);
                    aA[1] = dot2(p3, bwA[4 * r + 3], aA[1]);
                }
                float partU = aU[0] + aU[1];
                float partA = aA[0] + aA[1];
                if (kq == 1) partA += pc[ph];

                if (kq) pbuf[kq - 1][col] = make_float2(partU, partA);
                __syncthreads();

                if (kq == 0) {
                    const float2 q0 = pbuf[0][col];
                    const float2 q1 = pbuf[1][col];
                    const float2 q2 = pbuf[2][col];
                    const float yU = partU + q0.x + q1.x + q2.x + pc[ph];
                    const float yA = partA + q0.y + q1.y + q2.y;
                    const float cand  = fast_tanh(yU);
                    const float alpha = fast_sigmoid(yA);
                    const float hn = hprev + alpha * (cand - hprev);
                    hprev = hn;
                    hst[ph] = hn;
                    hbuf[(t + 1) & 1][col] = (_Float16)hn;
                }
                __syncthreads();
            }

            // chunk flush: h0 rows -> global (f16, U-half of pre0 rows)
            if (kq == 0) {
                #pragma unroll
                for (int k = 0; k < 8; ++k)
                    rowbase[(size_t)(t0 + k) * RS + col] = (_Float16)hst[k];
            }
            if (kq < 2) {
                #pragma unroll
                for (int k = 0; k < 8; ++k) pc[k] = pn[k];
            }

            __syncthreads();   // all waves drained their chunk stores
            if (tid == 0) {
                __threadfence();
                __hip_atomic_store(prog + b, (t0 >> 3) + 1,
                                   __ATOMIC_RELEASE, __HIP_MEMORY_SCOPE_AGENT);
            }
        }

        if (kq == 0) hfin[b * Hn + col] = hprev;

    } else {
        // ========================= layer 1 =========================
        const int b = blockIdx.x - Bn;

        // ---- MFMA B fragments: wave w handles ntg = {2w, 2w+1} of 32 tiles
        //      (ntg<16: U cols via Wih1; ntg>=16: A cols via Wax1) ----
        f16x8 bfr0[8], bfr1[8];
        float biasv0, biasv1;
        int cg0, cg1;   // preL column for publish
        {
            const int ntgA = 2 * w, ntgB = 2 * w + 1;
            const float* __restrict__ WmA = (ntgA < 16) ? Wih1 : Wax1;
            const float* __restrict__ WmB = (ntgB < 16) ? Wih1 : Wax1;
            const int nA = 16 * (ntgA & 15) + cl;
            const int nB = 16 * (ntgB & 15) + cl;
            biasv0 = (ntgA < 16) ? bh1[nA] : ba1[nA];
            biasv1 = (ntgB < 16) ? bh1[nB] : ba1[nB];
            cg0 = (ntgA < 16) ? nA : (Hn + nA);
            cg1 = (ntgB < 16) ? nB : (Hn + nB);
            #pragma unroll
            for (int kc = 0; kc < 8; ++kc) {
                const int k0 = 32 * kc + 8 * g;
                f16x8 fa, fb;
                #pragma unroll
                for (int jj = 0; jj < 8; ++jj) {
                    fa[jj] = (_Float16)WmA[(size_t)(k0 + jj) * Hn + nA];
                    fb[jj] = (_Float16)WmB[(size_t)(k0 + jj) * Hn + nB];
                }
                bfr0[kc] = fa;
                bfr1[kc] = fb;
            }
        }

        // ---- scan weights (Whh1 / Wah1), R9 K-split layout ----
        h2 bwU[32], bwA[32];
        #pragma unroll
        for (int i = 0; i < 32; ++i) {
            const int k0 = 64 * kq + 2 * i;
            h2 u, a;
            u.x = (_Float16)WU1[(size_t)k0 * Hn + col];
            u.y = (_Float16)WU1[(size_t)(k0 + 1) * Hn + col];
            a.x = (_Float16)WA1[(size_t)k0 * Hn + col];
            a.y = (_Float16)WA1[(size_t)(k0 + 1) * Hn + col];
            bwU[i] = u;
            bwA[i] = a;
        }

        _Float16* __restrict__ rowbase = pre + (size_t)b * Tn * RS;
        float* __restrict__ outb = outf + (size_t)b * Tn * Hn;
        float hprev = 0.0f;

        if (tid < Hn) hbuf[0][tid] = (_Float16)0.0f;
        __syncthreads();

        for (int c = 0; c < Tn / 8; ++c) {
            const int t0 = 8 * c;

            // ---- acquire layer-0 chunk ----
            if (tid == 0) {
                while (__hip_atomic_load(prog + b, __ATOMIC_ACQUIRE,
                                         __HIP_MEMORY_SCOPE_AGENT) <= c)
                    __builtin_amdgcn_s_sleep(2);
            }
            __syncthreads();

            // ---- h0 rows -> LDS (8 x 256 f16; 1 u32 per thread) ----
            {
                const int r  = tid >> 7;
                const int c2 = tid & 127;
                const unsigned int v = *reinterpret_cast<const unsigned int*>(
                    rowbase + (size_t)(t0 + r) * RS + 2 * c2);
                *reinterpret_cast<unsigned int*>(&h0t[r][2 * c2]) = v;
            }
            __syncthreads();

            // ---- MFMA mini-GEMM: pre1 rows (M=8) -> preL ----
            {
                f16x8 af[8];
                #pragma unroll
                for (int kc = 0; kc < 8; ++kc)
                    af[kc] = *reinterpret_cast<const f16x8*>(&h0t[cl & 7][32 * kc + 8 * g]);

                const f32x4 z = {0.0f, 0.0f, 0.0f, 0.0f};
                f32x4 a0 = __builtin_amdgcn_mfma_f32_16x16x32_f16(af[0], bfr0[0], z, 0, 0, 0);
                f32x4 a1 = __builtin_amdgcn_mfma_f32_16x16x32_f16(af[0], bfr1[0], z, 0, 0, 0);
                #pragma unroll
                for (int kc = 1; kc < 8; ++kc) {
                    a0 = __builtin_amdgcn_mfma_f32_16x16x32_f16(af[kc], bfr0[kc], a0, 0, 0, 0);
                    a1 = __builtin_amdgcn_mfma_f32_16x16x32_f16(af[kc], bfr1[kc], a1, 0, 0, 0);
                }
                // D layout: col = lane&15, row = (lane>>4)*4 + reg; rows 0-7 valid
                if (lane < 32) {
                    const int r0 = (lane >> 4) * 4;
                    #pragma unroll
                    for (int ri = 0; ri < 4; ++ri) {
                        preL[r0 + ri][cg0] = (_Float16)(a0[ri] + biasv0);
                        preL[r0 + ri][cg1] = (_Float16)(a1[ri] + biasv1);
                    }
                }
            }
            __syncthreads();

            // ---- 8 scan steps (pre from preL) ----
            float hst[8];
            #pragma unroll
            for (int ph = 0; ph < 8; ++ph) {
                const int t = t0 + ph;
                const f16x8* __restrict__ hb =
                    reinterpret_cast<const f16x8*>(&hbuf[t & 1][64 * kq]);

                float aU[2] = {0.0f, 0.0f};
                float aA[2] = {0.0f, 0.0f};
                #pragma unroll
                for (int r = 0; r < 8; ++r) {
                    const f16x8 v = hb[r];
                    const h2 p0 = __builtin_shufflevector(v, v, 0, 1);
                    const h2 p1 = __builtin_shufflevector(v, v, 2, 3);
                    const h2 p2 = __builtin_shufflevector(v, v, 4, 5);
                    const h2 p3 = __builtin_shufflevector(v, v, 6, 7);
                    aU[0] = dot2(p0, bwU[4 * r + 0], aU[0]);
                    aU[1] = dot2(p1, bwU[4 * r + 1], aU[1]);
                    aU[0] = dot2(p2, bwU[4 * r + 2], aU[0]);
                    aU[1] = dot2(p3, bwU[4 * r + 3], aU[1]);
                    aA[0] = dot2(p0, bwA[4 * r + 0], aA[0]);
                    aA[1] = dot2(p1, bwA[4 * r + 1], aA[1]);
                    aA[0] = dot2(p2, bwA[4 * r + 2], aA[0]);
                    aA[1] = dot2(p3, bwA[4 * r + 3], aA[1]);
                }
                const float partU = aU[0] + aU[1];
                const float partA = aA[0] + aA[1];

                if (kq) pbuf[kq - 1][col] = make_float2(partU, partA);
                __syncthreads();

                if (kq == 0) {
                    const float2 q0 = pbuf[0][col];
                    const float2 q1 = pbuf[1][col];
                    const float2 q2 = pbuf[2][col];
                    const float yU = partU + q0.x + q1.x + q2.x + (float)preL[ph][col];
                    const float yA = partA + q0.y + q1.y + q2.y + (float)preL[ph][Hn + col];
                    const float cand  = fast_tanh(yU);
                    const float alpha = fast_sigmoid(yA);
                    const float hn = hprev + alpha * (cand - hprev);
                    hprev = hn;
                    hst[ph] = hn;
                    hbuf[(t + 1) & 1][col] = (_Float16)hn;
                }
                __syncthreads();
            }

            // ---- chunk flush: outputs f32 (overwrites consumed pre0 bytes) ----
            if (kq == 0) {
                #pragma unroll
                for (int k = 0; k < 8; ++k)
                    outb[(size_t)(t0 + k) * Hn + col] = hst[k];
            }
        }

        if (kq == 0) hfin[Bn * Hn + b * Hn + col] = hprev;
    }
}

extern "C" void kernel_launch(void* const* d_in, const int* in_sizes, int n_in,
                              void* d_out, int out_size, void* d_ws, size_t ws_size,
                              hipStream_t stream) {
    const float* X    = (const float*)d_in[0];
    const float* Wih0 = (const float*)d_in[1];
    const float* Whh0 = (const float*)d_in[2];
    const float* bh0  = (const float*)d_in[3];
    const float* Wax0 = (const float*)d_in[4];
    const float* Wah0 = (const float*)d_in[5];
    const float* ba0  = (const float*)d_in[6];
    const float* Wih1 = (const float*)d_in[7];
    const float* Whh1 = (const float*)d_in[8];
    const float* bh1  = (const float*)d_in[9];
    const float* Wax1 = (const float*)d_in[10];
    const float* Wah1 = (const float*)d_in[11];
    const float* ba1  = (const float*)d_in[12];

    float* outf = (float*)d_out;
    float* hfin = outf + (size_t)Bn * Tn * Hn;
    _Float16* pre = (_Float16*)d_out;
    int* prog = (int*)d_ws;

    hipMemsetAsync(prog, 0, Bn * sizeof(int), stream);
    gemm_x_kernel<<<dim3((Bn * Tn) / 64, 2), 256, 0, stream>>>(X, Wih0, bh0, Wax0, ba0, pre);
    fused_scan<<<dim3(2 * Bn), 1024, 0, stream>>>(pre, Whh0, Wah0,
                                                  Wih1, Wax1, bh1, ba1,
                                                  Whh1, Wah1, outf, hfin, prog);
}

// Round 11
// 2621.289 us; speedup vs baseline: 1.6780x; 1.4622x over previous
//
#include <hip/hip_runtime.h>

#define Bn 64
#define Tn 2048
#define In 128
#define Hn 256
#define RS 512  // row stride in f16 elements for pre/out rows (1024 B)

#define H0S (Hn + 8)       // h0t row stride (f16 elems)
#define PLS (2 * Hn + 8)   // preL row stride (f16 elems)

typedef _Float16 h2 __attribute__((ext_vector_type(2)));
typedef _Float16 f16x8 __attribute__((ext_vector_type(8)));
typedef float f32x4 __attribute__((ext_vector_type(4)));

__device__ __forceinline__ float fast_sigmoid(float x) {
    return 1.0f / (1.0f + __expf(-x));
}
__device__ __forceinline__ float fast_tanh(float x) {
    return 2.0f / (1.0f + __expf(-2.0f * x)) - 1.0f;
}
__device__ __forceinline__ h2 bc2(float f) {
    return __builtin_bit_cast(h2, f);
}

#if __has_builtin(__builtin_amdgcn_fdot2)
__device__ __forceinline__ float dot2(h2 a, h2 b, float c) {
    return __builtin_amdgcn_fdot2(a, b, c, false);
}
#else
__device__ __forceinline__ float dot2(h2 a, h2 b, float c) {
    return c + (float)a.x * (float)b.x + (float)a.y * (float)b.y;
}
#endif

// ---------------------------------------------------------------------------
// K1: pre0[m][512] (f16, in d_out) = X[m][0:128] @ [Wih0 | Wax0] + [bh0 | ba0]
// ---------------------------------------------------------------------------
__global__ void gemm_x_kernel(const float* __restrict__ X,
                              const float* __restrict__ Wih0, const float* __restrict__ bh0,
                              const float* __restrict__ Wax0, const float* __restrict__ ba0,
                              _Float16* __restrict__ pre)
{
    __shared__ __align__(16) float Xs[64 * In];  // 32 KB
    const int m0 = blockIdx.x * 64;
    const int s  = blockIdx.y;
    const float* __restrict__ W    = s ? Wax0 : Wih0;
    const float* __restrict__ bias = s ? ba0  : bh0;

    {
        const float4* __restrict__ src = reinterpret_cast<const float4*>(X + (size_t)m0 * In);
        float4* __restrict__ dst = reinterpret_cast<float4*>(Xs);
        #pragma unroll
        for (int i = 0; i < 8; ++i) dst[threadIdx.x + 256 * i] = src[threadIdx.x + 256 * i];
    }
    __syncthreads();

    const int c  = threadIdx.x & 63;
    const int rg = threadIdx.x >> 6;
    const int mr = rg * 16;

    float acc[16][4];
    #pragma unroll
    for (int u = 0; u < 4; ++u) {
        const float bv = bias[c + 64 * u];
        #pragma unroll
        for (int r = 0; r < 16; ++r) acc[r][u] = bv;
    }

    const float4* __restrict__ Xs4 = reinterpret_cast<const float4*>(Xs);
    #pragma unroll 4
    for (int kc = 0; kc < 32; ++kc) {
        float wv[4][4];
        #pragma unroll
        for (int kk = 0; kk < 4; ++kk)
            #pragma unroll
            for (int u = 0; u < 4; ++u)
                wv[kk][u] = W[(size_t)(4 * kc + kk) * Hn + c + 64 * u];
        #pragma unroll
        for (int r = 0; r < 16; ++r) {
            const float4 xv = Xs4[(mr + r) * 32 + kc];
            #pragma unroll
            for (int u = 0; u < 4; ++u)
                acc[r][u] += xv.x * wv[0][u] + xv.y * wv[1][u] + xv.z * wv[2][u] + xv.w * wv[3][u];
        }
    }

    #pragma unroll
    for (int r = 0; r < 16; ++r)
        #pragma unroll
        for (int u = 0; u < 4; ++u)
            pre[(size_t)(m0 + mr + r) * RS + s * Hn + c + 64 * u] = (_Float16)acc[r][u];
}

// ---------------------------------------------------------------------------
// Fused two-layer scan, cross-block chunk pipeline, GROUP-AMORTIZED fences.
//
// R10 post-mortem: per-chunk agent-scope release (buffer_wbl2) + acquire-poll
// (buffer_inv per poll) thrashed every XCD L2 -> consumer chunk 32.5k cy
// (2x standalone). This version:
//  - prog[b] counts GROUPS of 4 chunks (32 steps): one wbl2 per group.
//  - consumer polls RELAXED (no inv), one ACQUIRE load after success: one
//    inv per group.
//  - consumer per group: load 32 h0 rows -> LDS, M=32 MFMA mini-GEMM
//    (full 16-row D tiles), then 32 scan steps reading preL.
// ---------------------------------------------------------------------------
__global__ __launch_bounds__(1024, 4)
void fused_scan(_Float16* __restrict__ pre,
                const float* __restrict__ WU0, const float* __restrict__ WA0,
                const float* __restrict__ Wih1, const float* __restrict__ Wax1,
                const float* __restrict__ bh1,  const float* __restrict__ ba1,
                const float* __restrict__ WU1,  const float* __restrict__ WA1,
                float* __restrict__ outf, float* __restrict__ hfin,
                int* __restrict__ prog)
{
    __shared__ __align__(16) _Float16 hbuf[2][Hn];    // 1 KB
    __shared__ __align__(16) float2   pbuf[3][Hn];    // 6 KB
    __shared__ __align__(16) _Float16 h0t[32][H0S];   // 16.9 KB
    __shared__ __align__(16) _Float16 preL[32][PLS];  // 33.3 KB

    const int tid  = threadIdx.x;
    const int col  = tid & 255;
    const int kq   = tid >> 8;
    const int lane = tid & 63;
    const int w    = tid >> 6;
    const int g    = lane >> 4;
    const int cl   = lane & 15;

    if (blockIdx.x < Bn) {
        // ========================= layer 0 (producer) =========================
        const int b = blockIdx.x;
        h2 bwU[32], bwA[32];
        #pragma unroll
        for (int i = 0; i < 32; ++i) {
            const int k0 = 64 * kq + 2 * i;
            h2 u, a;
            u.x = (_Float16)WU0[(size_t)k0 * Hn + col];
            u.y = (_Float16)WU0[(size_t)(k0 + 1) * Hn + col];
            a.x = (_Float16)WA0[(size_t)k0 * Hn + col];
            a.y = (_Float16)WA0[(size_t)(k0 + 1) * Hn + col];
            bwU[i] = u;
            bwA[i] = a;
        }

        _Float16* __restrict__ rowbase = pre + (size_t)b * Tn * RS;
        float hprev = 0.0f;

        if (tid < Hn) hbuf[0][tid] = (_Float16)0.0f;
        float pc[8];
        if (kq < 2) {
            const int off = kq ? Hn : 0;
            #pragma unroll
            for (int k = 0; k < 8; ++k)
                pc[k] = (float)rowbase[(size_t)k * RS + off + col];
        }
        __syncthreads();

        for (int t0 = 0; t0 < Tn; t0 += 8) {
            float pn[8];
            if (kq < 2) {
                const int off = kq ? Hn : 0;
                #pragma unroll
                for (int k = 0; k < 8; ++k) {
                    int tn = t0 + 8 + k;
                    if (tn > Tn - 1) tn = Tn - 1;
                    pn[k] = (float)rowbase[(size_t)tn * RS + off + col];
                }
            }

            float hst[8];

            #pragma unroll
            for (int ph = 0; ph < 8; ++ph) {
                const int t = t0 + ph;
                const f16x8* __restrict__ hb =
                    reinterpret_cast<const f16x8*>(&hbuf[t & 1][64 * kq]);

                float aU[2] = {0.0f, 0.0f};
                float aA[2] = {0.0f, 0.0f};
                #pragma unroll
                for (int r = 0; r < 8; ++r) {
                    const f16x8 v = hb[r];
                    const h2 p0 = __builtin_shufflevector(v, v, 0, 1);
                    const h2 p1 = __builtin_shufflevector(v, v, 2, 3);
                    const h2 p2 = __builtin_shufflevector(v, v, 4, 5);
                    const h2 p3 = __builtin_shufflevector(v, v, 6, 7);
                    aU[0] = dot2(p0, bwU[4 * r + 0], aU[0]);
                    aU[1] = dot2(p1, bwU[4 * r + 1], aU[1]);
                    aU[0] = dot2(p2, bwU[4 * r + 2], aU[0]);
                    aU[1] = dot2(p3, bwU[4 * r + 3], aU[1]);
                    aA[0] = dot2(p0, bwA[4 * r + 0], aA[0]);
                    aA[1] = dot2(p1, bwA[4 * r + 1], aA[1]);
                    aA[0] = dot2(p2, bwA[4 * r + 2], aA[0]);
                    aA[1] = dot2(p3, bwA[4 * r + 3], aA[1]);
                }
                float partU = aU[0] + aU[1];
                float partA = aA[0] + aA[1];
                if (kq == 1) partA += pc[ph];

                if (kq) pbuf[kq - 1][col] = make_float2(partU, partA);
                __syncthreads();

                if (kq == 0) {
                    const float2 q0 = pbuf[0][col];
                    const float2 q1 = pbuf[1][col];
                    const float2 q2 = pbuf[2][col];
                    const float yU = partU + q0.x + q1.x + q2.x + pc[ph];
                    const float yA = partA + q0.y + q1.y + q2.y;
                    const float cand  = fast_tanh(yU);
                    const float alpha = fast_sigmoid(yA);
                    const float hn = hprev + alpha * (cand - hprev);
                    hprev = hn;
                    hst[ph] = hn;
                    hbuf[(t + 1) & 1][col] = (_Float16)hn;
                }
                __syncthreads();
            }

            // chunk flush: h0 rows -> global (f16, U-half of pre0 rows)
            if (kq == 0) {
                #pragma unroll
                for (int k = 0; k < 8; ++k)
                    rowbase[(size_t)(t0 + k) * RS + col] = (_Float16)hst[k];
            }
            if (kq < 2) {
                #pragma unroll
                for (int k = 0; k < 8; ++k) pc[k] = pn[k];
            }

            // group boundary (every 4th chunk): drain stores, ONE fence, release
            if (((t0 >> 3) & 3) == 3) {
                __syncthreads();   // vmcnt(0): all waves' chunk stores complete
                if (tid == 0) {
                    __threadfence();   // L2 writeback -> device-visible
                    __hip_atomic_store(prog + b, (t0 >> 5) + 1,
                                       __ATOMIC_RELEASE, __HIP_MEMORY_SCOPE_AGENT);
                }
            }
        }

        if (kq == 0) hfin[b * Hn + col] = hprev;

    } else {
        // ========================= layer 1 (consumer) =========================
        const int b = blockIdx.x - Bn;

        // ---- MFMA B fragments: wave w covers ntg = {2w, 2w+1} of 32 N-tiles
        //      (ntg<16: U cols via Wih1; ntg>=16: A cols via Wax1) ----
        f16x8 bfr0[8], bfr1[8];
        float biasv0, biasv1;
        int cg0, cg1;   // preL column for publish
        {
            const int ntgA = 2 * w, ntgB = 2 * w + 1;
            const float* __restrict__ WmA = (ntgA < 16) ? Wih1 : Wax1;
            const float* __restrict__ WmB = (ntgB < 16) ? Wih1 : Wax1;
            const int nA = 16 * (ntgA & 15) + cl;
            const int nB = 16 * (ntgB & 15) + cl;
            biasv0 = (ntgA < 16) ? bh1[nA] : ba1[nA];
            biasv1 = (ntgB < 16) ? bh1[nB] : ba1[nB];
            cg0 = (ntgA < 16) ? nA : (Hn + nA);
            cg1 = (ntgB < 16) ? nB : (Hn + nB);
            #pragma unroll
            for (int kc = 0; kc < 8; ++kc) {
                const int k0 = 32 * kc + 8 * g;
                f16x8 fa, fb;
                #pragma unroll
                for (int jj = 0; jj < 8; ++jj) {
                    fa[jj] = (_Float16)WmA[(size_t)(k0 + jj) * Hn + nA];
                    fb[jj] = (_Float16)WmB[(size_t)(k0 + jj) * Hn + nB];
                }
                bfr0[kc] = fa;
                bfr1[kc] = fb;
            }
        }

        // ---- scan weights (Whh1 / Wah1), K-split layout ----
        h2 bwU[32], bwA[32];
        #pragma unroll
        for (int i = 0; i < 32; ++i) {
            const int k0 = 64 * kq + 2 * i;
            h2 u, a;
            u.x = (_Float16)WU1[(size_t)k0 * Hn + col];
            u.y = (_Float16)WU1[(size_t)(k0 + 1) * Hn + col];
            a.x = (_Float16)WA1[(size_t)k0 * Hn + col];
            a.y = (_Float16)WA1[(size_t)(k0 + 1) * Hn + col];
            bwU[i] = u;
            bwA[i] = a;
        }

        _Float16* __restrict__ rowbase = pre + (size_t)b * Tn * RS;
        float* __restrict__ outb = outf + (size_t)b * Tn * Hn;
        float hprev = 0.0f;

        if (tid < Hn) hbuf[0][tid] = (_Float16)0.0f;
        __syncthreads();

        for (int grp = 0; grp < Tn / 32; ++grp) {
            const int t0g = 32 * grp;

            // ---- acquire group: relaxed poll, single acquire load ----
            if (tid == 0) {
                while (__hip_atomic_load(prog + b, __ATOMIC_RELAXED,
                                         __HIP_MEMORY_SCOPE_AGENT) <= grp)
                    __builtin_amdgcn_s_sleep(8);
                (void)__hip_atomic_load(prog + b, __ATOMIC_ACQUIRE,
                                        __HIP_MEMORY_SCOPE_AGENT);
            }
            __syncthreads();   // also orders h0t reuse across groups

            // ---- 32 h0 rows -> LDS (4 u32 per thread) ----
            #pragma unroll
            for (int q = 0; q < 4; ++q) {
                const int id  = tid + 1024 * q;
                const int r   = id >> 7;
                const int off = id & 127;
                const unsigned int v = *reinterpret_cast<const unsigned int*>(
                    rowbase + (size_t)(t0g + r) * RS + 2 * off);
                *reinterpret_cast<unsigned int*>(&h0t[r][2 * off]) = v;
            }
            __syncthreads();

            // ---- M=32 MFMA mini-GEMM: pre1 rows -> preL ----
            {
                #pragma unroll
                for (int mt = 0; mt < 2; ++mt) {
                    f16x8 af[8];
                    #pragma unroll
                    for (int kc = 0; kc < 8; ++kc)
                        af[kc] = *reinterpret_cast<const f16x8*>(
                            &h0t[16 * mt + cl][32 * kc + 8 * g]);

                    const f32x4 z = {0.0f, 0.0f, 0.0f, 0.0f};
                    f32x4 a0 = __builtin_amdgcn_mfma_f32_16x16x32_f16(af[0], bfr0[0], z, 0, 0, 0);
                    f32x4 a1 = __builtin_amdgcn_mfma_f32_16x16x32_f16(af[0], bfr1[0], z, 0, 0, 0);
                    #pragma unroll
                    for (int kc = 1; kc < 8; ++kc) {
                        a0 = __builtin_amdgcn_mfma_f32_16x16x32_f16(af[kc], bfr0[kc], a0, 0, 0, 0);
                        a1 = __builtin_amdgcn_mfma_f32_16x16x32_f16(af[kc], bfr1[kc], a1, 0, 0, 0);
                    }
                    // D layout: col = lane&15, row = (lane>>4)*4 + reg (all 16 valid)
                    const int r0 = 16 * mt + (lane >> 4) * 4;
                    #pragma unroll
                    for (int ri = 0; ri < 4; ++ri) {
                        preL[r0 + ri][cg0] = (_Float16)(a0[ri] + biasv0);
                        preL[r0 + ri][cg1] = (_Float16)(a1[ri] + biasv1);
                    }
                }
            }
            __syncthreads();

            // ---- 32 scan steps (pre from preL), per-chunk outf flush ----
            for (int cc = 0; cc < 4; ++cc) {
                const int t0 = t0g + 8 * cc;
                float hst[8];
                #pragma unroll
                for (int ph = 0; ph < 8; ++ph) {
                    const int t = t0 + ph;
                    const int pr = 8 * cc + ph;   // preL row
                    const f16x8* __restrict__ hb =
                        reinterpret_cast<const f16x8*>(&hbuf[t & 1][64 * kq]);

                    float aU[2] = {0.0f, 0.0f};
                    float aA[2] = {0.0f, 0.0f};
                    #pragma unroll
                    for (int r = 0; r < 8; ++r) {
                        const f16x8 v = hb[r];
                        const h2 p0 = __builtin_shufflevector(v, v, 0, 1);
                        const h2 p1 = __builtin_shufflevector(v, v, 2, 3);
                        const h2 p2 = __builtin_shufflevector(v, v, 4, 5);
                        const h2 p3 = __builtin_shufflevector(v, v, 6, 7);
                        aU[0] = dot2(p0, bwU[4 * r + 0], aU[0]);
                        aU[1] = dot2(p1, bwU[4 * r + 1], aU[1]);
                        aU[0] = dot2(p2, bwU[4 * r + 2], aU[0]);
                        aU[1] = dot2(p3, bwU[4 * r + 3], aU[1]);
                        aA[0] = dot2(p0, bwA[4 * r + 0], aA[0]);
                        aA[1] = dot2(p1, bwA[4 * r + 1], aA[1]);
                        aA[0] = dot2(p2, bwA[4 * r + 2], aA[0]);
                        aA[1] = dot2(p3, bwA[4 * r + 3], aA[1]);
                    }
                    const float partU = aU[0] + aU[1];
                    const float partA = aA[0] + aA[1];

                    if (kq) pbuf[kq - 1][col] = make_float2(partU, partA);
                    __syncthreads();

                    if (kq == 0) {
                        const float2 q0 = pbuf[0][col];
                        const float2 q1 = pbuf[1][col];
                        const float2 q2 = pbuf[2][col];
                        const float yU = partU + q0.x + q1.x + q2.x + (float)preL[pr][col];
                        const float yA = partA + q0.y + q1.y + q2.y + (float)preL[pr][Hn + col];
                        const float cand  = fast_tanh(yU);
                        const float alpha = fast_sigmoid(yA);
                        const float hn = hprev + alpha * (cand - hprev);
                        hprev = hn;
                        hst[ph] = hn;
                        hbuf[(t + 1) & 1][col] = (_Float16)hn;
                    }
                    __syncthreads();
                }

                // chunk flush: outputs f32 (overwrites consumed pre0 bytes)
                if (kq == 0) {
                    #pragma unroll
                    for (int k = 0; k < 8; ++k)
                        outb[(size_t)(t0 + k) * Hn + col] = hst[k];
                }
            }
        }

        if (kq == 0) hfin[Bn * Hn + b * Hn + col] = hprev;
    }
}

extern "C" void kernel_launch(void* const* d_in, const int* in_sizes, int n_in,
                              void* d_out, int out_size, void* d_ws, size_t ws_size,
                              hipStream_t stream) {
    const float* X    = (const float*)d_in[0];
    const float* Wih0 = (const float*)d_in[1];
    const float* Whh0 = (const float*)d_in[2];
    const float* bh0  = (const float*)d_in[3];
    const float* Wax0 = (const float*)d_in[4];
    const float* Wah0 = (const float*)d_in[5];
    const float* ba0  = (const float*)d_in[6];
    const float* Wih1 = (const float*)d_in[7];
    const float* Whh1 = (const float*)d_in[8];
    const float* bh1  = (const float*)d_in[9];
    const float* Wax1 = (const float*)d_in[10];
    const float* Wah1 = (const float*)d_in[11];
    const float* ba1  = (const float*)d_in[12];

    float* outf = (float*)d_out;
    float* hfin = outf + (size_t)Bn * Tn * Hn;
    _Float16* pre = (_Float16*)d_out;
    int* prog = (int*)d_ws;

    hipMemsetAsync(prog, 0, Bn * sizeof(int), stream);
    gemm_x_kernel<<<dim3((Bn * Tn) / 64, 2), 256, 0, stream>>>(X, Wih0, bh0, Wax0, ba0, pre);
    fused_scan<<<dim3(2 * Bn), 1024, 0, stream>>>(pre, Whh0, Wah0,
                                                  Wih1, Wax1, bh1, ba1,
                                                  Whh1, Wah1, outf, hfin, prog);
}